// Round 6
// baseline (798.775 us; speedup 1.0000x reference)
//
#include <hip/hip_runtime.h>

#define T_SEQ   2048
#define C_DIM   1024
#define B_BATCH 2
#define H_HEADS 16
#define D_HEAD  64
#define EPS_Y   1e-6f

typedef short bf16x8 __attribute__((ext_vector_type(8)));  // 8 bf16 (4 VGPR)
typedef float f32x4  __attribute__((ext_vector_type(4)));  // MFMA accumulator

// split f into hi + lo bf16 (hi = RNE(f), lo = RNE(f - hi); f-hi exact)
__device__ __forceinline__ void split_bf16(float f, unsigned short& h, unsigned short& l) {
  unsigned int u = __float_as_uint(f);
  unsigned int hb = (u + 0x7fffu + ((u >> 16) & 1u)) >> 16;
  h = (unsigned short)hb;
  float hf = __uint_as_float(hb << 16);
  float res = f - hf;
  unsigned int v = __float_as_uint(res);
  l = (unsigned short)((v + 0x7fffu + ((v >> 16) & 1u)) >> 16);
}

// ---------------------------------------------------------------------------
// Streaming split: fp32[n] -> hi bf16[n], lo bf16[n].  n4 = n/4.
// ---------------------------------------------------------------------------
__global__ __launch_bounds__(256) void convert_split(
    const float* __restrict__ in, unsigned short* __restrict__ hi,
    unsigned short* __restrict__ lo, int n4) {
  int idx = blockIdx.x * 256 + threadIdx.x;
  int stride = gridDim.x * 256;
  for (int i = idx; i < n4; i += stride) {
    float4 v = ((const float4*)in)[i];
    ushort4 h, l;
    split_bf16(v.x, h.x, l.x);
    split_bf16(v.y, h.y, l.y);
    split_bf16(v.z, h.z, l.z);
    split_bf16(v.w, h.w, l.w);
    ((ushort4*)hi)[i] = h;
    ((ushort4*)lo)[i] = l;
  }
}

// ---------------------------------------------------------------------------
// Transpose + split: W [K][N] fp32 row-major -> th/tl [N][K] bf16.
// 64x64 tiles via LDS (pad 65). grid = (N/64, K/64), 256 threads.
// ---------------------------------------------------------------------------
__global__ __launch_bounds__(256) void transpose_split(
    const float* __restrict__ W, unsigned short* __restrict__ th,
    unsigned short* __restrict__ tl, int K, int N) {
  __shared__ float tile[64][65];
  const int bk = blockIdx.y * 64;     // K block
  const int bn = blockIdx.x * 64;     // N block
  const int t  = threadIdx.x;
  const int r  = t >> 2;              // 0..63
  const int c0 = (t & 3) << 4;        // 0,16,32,48

  // load W[bk+r][bn+c0 .. +15] (coalesced float4)
#pragma unroll
  for (int c = 0; c < 16; c += 4) {
    float4 v = *(const float4*)(W + (size_t)(bk + r) * N + bn + c0 + c);
    tile[r][c0 + c + 0] = v.x; tile[r][c0 + c + 1] = v.y;
    tile[r][c0 + c + 2] = v.z; tile[r][c0 + c + 3] = v.w;
  }
  __syncthreads();

  // write out[bn+r][bk+c0 .. +15] = tile[c0+c][r]
#pragma unroll
  for (int c = 0; c < 16; c += 4) {
    ushort4 h, l;
    split_bf16(tile[c0 + c + 0][r], h.x, l.x);
    split_bf16(tile[c0 + c + 1][r], h.y, l.y);
    split_bf16(tile[c0 + c + 2][r], h.z, l.z);
    split_bf16(tile[c0 + c + 3][r], h.w, l.w);
    size_t off = (size_t)(bn + r) * K + bk + c0 + c;
    *(ushort4*)(th + off) = h;
    *(ushort4*)(tl + off) = l;
  }
}

// ---------------------------------------------------------------------------
// Split-bf16 MFMA GEMM: C[M][N] fp32 = (Ah+Al)[M][K] x (Bh+Bl stored as
// B^T [N][K]). 128x128 tile, BK=32, 256 threads = 4 waves (2x2 of 64x64).
// Per fragment: acc = Ahi*Bhi + Ahi*Blo + Alo*Bhi (lo*lo dropped, ~2^-18).
// Fragment layout (HW-verified m89/m92/m97): A/B lane l reads row (l&15),
// k = (l>>4)*8..+8 contiguous; C/D col = l&15, row = (l>>4)*4 + reg.
// LDS arrays alignas(16): b128 LDS ops require 16B-aligned base (short
// arrays only guarantee 2B naturally).
// ---------------------------------------------------------------------------
__global__ __launch_bounds__(256) void gemm_split(
    const unsigned short* __restrict__ Ah, const unsigned short* __restrict__ Al,
    const unsigned short* __restrict__ Bh, const unsigned short* __restrict__ Bl,
    float* __restrict__ C, int M, int N, int K) {
  __shared__ alignas(16) short sAh[128][32], sAl[128][32];   // 8 KB each
  __shared__ alignas(16) short sBh[128][32], sBl[128][32];   // total 32 KB
  const int t  = threadIdx.x;
  const int l  = t & 63;
  const int w  = t >> 6;                 // wave 0..3
  const int bm = blockIdx.y * 128;
  const int bn = blockIdx.x * 128;
  const int wm = (w >> 1) * 64;          // wave row origin in tile
  const int wn = (w & 1) * 64;           // wave col origin in tile

  f32x4 acc[4][4] = {};

  for (int k0 = 0; k0 < K; k0 += 32) {
    // ---- stage 4 tiles (reg-staged, coalesced 16B) ----
#pragma unroll
    for (int r = 0; r < 2; ++r) {
      const int i   = r * 256 + t;       // 0..511
      const int row = i >> 2;            // 0..127
      const int k8  = (i & 3) << 3;      // 0,8,16,24
      const size_t ga = (size_t)(bm + row) * K + k0 + k8;
      const size_t gb = (size_t)(bn + row) * K + k0 + k8;
      *(bf16x8*)(&sAh[row][k8]) = *(const bf16x8*)(Ah + ga);
      *(bf16x8*)(&sAl[row][k8]) = *(const bf16x8*)(Al + ga);
      *(bf16x8*)(&sBh[row][k8]) = *(const bf16x8*)(Bh + gb);
      *(bf16x8*)(&sBl[row][k8]) = *(const bf16x8*)(Bl + gb);
    }
    __syncthreads();

    // ---- fragments ----
    bf16x8 ah[4], al4[4], bh[4], bl4[4];
    const int lr = l & 15;
    const int kk = (l >> 4) << 3;
#pragma unroll
    for (int mi = 0; mi < 4; ++mi) {
      const int row = wm + mi * 16 + lr;
      ah[mi]  = *(const bf16x8*)(&sAh[row][kk]);
      al4[mi] = *(const bf16x8*)(&sAl[row][kk]);
    }
#pragma unroll
    for (int ni = 0; ni < 4; ++ni) {
      const int row = wn + ni * 16 + lr;
      bh[ni]  = *(const bf16x8*)(&sBh[row][kk]);
      bl4[ni] = *(const bf16x8*)(&sBl[row][kk]);
    }

    // ---- MFMA: 3 per fragment (hi*hi, hi*lo, lo*hi) ----
#pragma unroll
    for (int mi = 0; mi < 4; ++mi)
#pragma unroll
      for (int ni = 0; ni < 4; ++ni) {
        acc[mi][ni] = __builtin_amdgcn_mfma_f32_16x16x32_bf16(ah[mi],  bh[ni],  acc[mi][ni], 0, 0, 0);
        acc[mi][ni] = __builtin_amdgcn_mfma_f32_16x16x32_bf16(ah[mi],  bl4[ni], acc[mi][ni], 0, 0, 0);
        acc[mi][ni] = __builtin_amdgcn_mfma_f32_16x16x32_bf16(al4[mi], bh[ni],  acc[mi][ni], 0, 0, 0);
      }
    __syncthreads();
  }

  // ---- epilogue: C/D layout col=l&15, row=(l>>4)*4+reg ----
  const int cr = (l >> 4) << 2;
  const int cc = l & 15;
#pragma unroll
  for (int mi = 0; mi < 4; ++mi)
#pragma unroll
    for (int ni = 0; ni < 4; ++ni) {
      const size_t base = (size_t)(bm + wm + mi * 16 + cr) * N + bn + wn + ni * 16 + cc;
#pragma unroll
      for (int r = 0; r < 4; ++r)
        C[base + (size_t)r * N] = acc[mi][ni][r];
    }
}

// ---------------------------------------------------------------------------
// Fused Yat causal attention (flash-style), fp32 compute.
// Inner loops float4-blocked (8x ds_read_b128 per 4 k-steps).
// Output written directly as split bf16 (hi/lo) for the Wout GEMM.
// LDS alignas(16): float4 LDS accesses require 16B-aligned base.
// ---------------------------------------------------------------------------
__global__ __launch_bounds__(256) void yat_attn(
    const float* __restrict__ qkv,
    unsigned short* __restrict__ oh, unsigned short* __restrict__ ol) {
  const int qb = blockIdx.x;            // q-block 0..31
  const int bh = blockIdx.y;            // 0..31
  const int b  = bh >> 4;
  const int h  = bh & 15;

  const float* base = qkv + (size_t)b * T_SEQ * 3 * C_DIM;
  const int qcol = h * D_HEAD;
  const int kcol = C_DIM + h * D_HEAD;
  const int vcol = 2 * C_DIM + h * D_HEAD;

  __shared__ alignas(16) float Qs[64][68];
  __shared__ alignas(16) float Kt[64][68];   // transposed K
  __shared__ alignas(16) float Vs[64][68];
  __shared__ alignas(16) float Ss[64][68];
  __shared__ float qn_row[64], kn_row[64];
  __shared__ float row_m[64], row_l[64], row_scale[64];

  const int t  = threadIdx.x;
  const int tm = t >> 4;
  const int tn = t & 15;
  const int i0 = tm * 4;
  const int d0 = tn * 4;

#pragma unroll
  for (int r = 0; r < 4; ++r) {
    const int i  = (t >> 4) + r * 16;
    const int d4 = (t & 15) * 4;
    float4 v = *(const float4*)(base + (size_t)(qb * 64 + i) * 3 * C_DIM + qcol + d4);
    *(float4*)(&Qs[i][d4]) = v;
  }
  if (t < 64) { row_m[t] = -INFINITY; row_l[t] = 0.f; }
  __syncthreads();

  {
    const int r = t >> 2, g = t & 3;
    float s = 0.f;
#pragma unroll
    for (int c = 0; c < 16; ++c) {
      float x = Qs[r][g * 16 + c];
      s = fmaf(x, x, s);
    }
    s += __shfl_xor(s, 1); s += __shfl_xor(s, 2);
    if (g == 0) qn_row[r] = s;
  }

  float o[4][4] = {};
  __syncthreads();

  for (int kb = 0; kb <= qb; ++kb) {
#pragma unroll
    for (int r = 0; r < 4; ++r) {
      const int j  = (t >> 4) + r * 16;
      const int d4 = (t & 15) * 4;
      const size_t row = (size_t)(kb * 64 + j) * 3 * C_DIM;
      float4 kv = *(const float4*)(base + row + kcol + d4);
      Kt[d4 + 0][j] = kv.x; Kt[d4 + 1][j] = kv.y;
      Kt[d4 + 2][j] = kv.z; Kt[d4 + 3][j] = kv.w;
      float4 vv = *(const float4*)(base + row + vcol + d4);
      *(float4*)(&Vs[j][d4]) = vv;
    }
    __syncthreads();

    {
      const int j = t >> 2, g = t & 3;
      float s = 0.f;
#pragma unroll
      for (int c = 0; c < 16; ++c) {
        float x = Kt[g * 16 + c][j];
        s = fmaf(x, x, s);
      }
      s += __shfl_xor(s, 1); s += __shfl_xor(s, 2);
      if (g == 0) kn_row[j] = s;
    }
    __syncthreads();

    // ---- S = Q K^T (float4-blocked over d), Yat transform + mask ----
    {
      float s[4][4] = {};
#pragma unroll
      for (int db = 0; db < 16; ++db) {
        float4 q4[4], kr[4];
#pragma unroll
        for (int i = 0; i < 4; ++i)
          q4[i] = *(const float4*)(&Qs[i0 + i][db * 4]);
#pragma unroll
        for (int dj = 0; dj < 4; ++dj)
          kr[dj] = *(const float4*)(&Kt[db * 4 + dj][d0]);
#pragma unroll
        for (int dj = 0; dj < 4; ++dj) {
          const float* krp = (const float*)&kr[dj];
#pragma unroll
          for (int i = 0; i < 4; ++i) {
            const float qv = ((const float*)&q4[i])[dj];
#pragma unroll
            for (int j = 0; j < 4; ++j)
              s[i][j] = fmaf(qv, krp[j], s[i][j]);
          }
        }
      }
      const bool diag = (kb == qb);
#pragma unroll
      for (int i = 0; i < 4; ++i) {
        const float qn = qn_row[i0 + i];
        const int gq = qb * 64 + i0 + i;
#pragma unroll
        for (int j = 0; j < 4; ++j) {
          const float dot = s[i][j];
          const float kn = kn_row[d0 + j];
          float sc = (dot * dot) / (qn + kn - 2.f * dot + EPS_Y);
          if (diag && (kb * 64 + d0 + j) > gq) sc = -INFINITY;
          Ss[i0 + i][d0 + j] = sc;
        }
      }
    }
    __syncthreads();

    {
      const int r = t >> 2, g = t & 3;
      float vals[16];
      float mloc = -INFINITY;
#pragma unroll
      for (int c = 0; c < 16; ++c) {
        vals[c] = Ss[r][g * 16 + c];
        mloc = fmaxf(mloc, vals[c]);
      }
      mloc = fmaxf(mloc, __shfl_xor(mloc, 1));
      mloc = fmaxf(mloc, __shfl_xor(mloc, 2));
      const float m_old = row_m[r];
      const float m_new = fmaxf(m_old, mloc);
      float ssum = 0.f;
#pragma unroll
      for (int c = 0; c < 16; ++c) {
        float p = __expf(vals[c] - m_new);
        Ss[r][g * 16 + c] = p;
        ssum += p;
      }
      ssum += __shfl_xor(ssum, 1);
      ssum += __shfl_xor(ssum, 2);
      if (g == 0) {
        const float rs = __expf(m_old - m_new);
        row_scale[r] = rs;
        row_l[r] = row_l[r] * rs + ssum;
        row_m[r] = m_new;
      }
    }
    __syncthreads();

    // ---- O = O*rescale + P @ V (float4-blocked over j) ----
    {
      float rs[4];
#pragma unroll
      for (int i = 0; i < 4; ++i) rs[i] = row_scale[i0 + i];
#pragma unroll
      for (int i = 0; i < 4; ++i)
#pragma unroll
        for (int j = 0; j < 4; ++j) o[i][j] *= rs[i];

#pragma unroll
      for (int jb = 0; jb < 16; ++jb) {
        float4 p4[4], vr[4];
#pragma unroll
        for (int i = 0; i < 4; ++i)
          p4[i] = *(const float4*)(&Ss[i0 + i][jb * 4]);
#pragma unroll
        for (int j = 0; j < 4; ++j)
          vr[j] = *(const float4*)(&Vs[jb * 4 + j][d0]);
#pragma unroll
        for (int j = 0; j < 4; ++j) {
          const float* vrp = (const float*)&vr[j];
#pragma unroll
          for (int i = 0; i < 4; ++i) {
            const float pv = ((const float*)&p4[i])[j];
#pragma unroll
            for (int dd = 0; dd < 4; ++dd)
              o[i][dd] = fmaf(pv, vrp[dd], o[i][dd]);
          }
        }
      }
    }
    __syncthreads();
  }

  // ---- normalize, split to bf16 hi/lo, write ----
#pragma unroll
  for (int i = 0; i < 4; ++i) {
    const float inv = 1.f / row_l[i0 + i];
    ushort4 hv, lv;
    split_bf16(o[i][0] * inv, hv.x, lv.x);
    split_bf16(o[i][1] * inv, hv.y, lv.y);
    split_bf16(o[i][2] * inv, hv.z, lv.z);
    split_bf16(o[i][3] * inv, hv.w, lv.w);
    const size_t off = ((size_t)b * T_SEQ + qb * 64 + i0 + i) * C_DIM + h * D_HEAD + d0;
    *(ushort4*)(oh + off) = hv;
    *(ushort4*)(ol + off) = lv;
  }
}

// ---------------------------------------------------------------------------
extern "C" void kernel_launch(void* const* d_in, const int* in_sizes, int n_in,
                              void* d_out, int out_size, void* d_ws, size_t ws_size,
                              hipStream_t stream) {
  const float* x    = (const float*)d_in[0];   // [B,T,C]
  const float* Wqkv = (const float*)d_in[1];   // [C,3C]
  const float* Wout = (const float*)d_in[2];   // [C,C]
  float* outp = (float*)d_out;                 // [B,T,C]

  const int M  = B_BATCH * T_SEQ;              // 4096
  const int C3 = 3 * C_DIM;                    // 3072

  // workspace layout (~100.7 MB total)
  float* qkv = (float*)d_ws;                                  // [M][3C] fp32
  unsigned short* xh  = (unsigned short*)(qkv + (size_t)M * C3);
  unsigned short* xl  = xh  + (size_t)M * C_DIM;
  unsigned short* wqh = xl  + (size_t)M * C_DIM;              // Wqkv^T [3C][C]
  unsigned short* wql = wqh + (size_t)C_DIM * C3;
  unsigned short* woh = wql + (size_t)C_DIM * C3;             // Wout^T [C][C]
  unsigned short* wol = woh + (size_t)C_DIM * C_DIM;
  unsigned short* ath = wol + (size_t)C_DIM * C_DIM;          // attn out hi
  unsigned short* atl = ath + (size_t)M * C_DIM;              // attn out lo

  // 1) split x
  convert_split<<<2048, 256, 0, stream>>>(x, xh, xl, M * C_DIM / 4);
  // 2) transpose+split weights
  {
    dim3 g1(C3 / 64, C_DIM / 64);
    transpose_split<<<g1, 256, 0, stream>>>(Wqkv, wqh, wql, C_DIM, C3);
    dim3 g2(C_DIM / 64, C_DIM / 64);
    transpose_split<<<g2, 256, 0, stream>>>(Wout, woh, wol, C_DIM, C_DIM);
  }
  // 3) qkv = x @ Wqkv (split-bf16 MFMA)
  {
    dim3 grid(C3 / 128, M / 128);
    gemm_split<<<grid, 256, 0, stream>>>(xh, xl, wqh, wql, qkv, M, C3, C_DIM);
  }
  // 4) fused Yat causal attention -> split bf16
  {
    dim3 grid(T_SEQ / 64, B_BATCH * H_HEADS);
    yat_attn<<<grid, 256, 0, stream>>>(qkv, ath, atl);
  }
  // 5) out = attn @ Wout (split-bf16 MFMA)
  {
    dim3 grid(C_DIM / 128, M / 128);
    gemm_split<<<grid, 256, 0, stream>>>(ath, atl, woh, wol, outp, M, C_DIM, C_DIM);
  }
  (void)in_sizes; (void)n_in; (void)out_size; (void)ws_size;
}

// Round 8
// 457.370 us; speedup vs baseline: 1.7465x; 1.7465x over previous
//
#include <hip/hip_runtime.h>

#define T_SEQ   2048
#define C_DIM   1024
#define B_BATCH 2
#define H_HEADS 16
#define D_HEAD  64
#define EPS_Y   1e-6f

typedef short bf16x8 __attribute__((ext_vector_type(8)));  // 8 bf16 (4 VGPR)
typedef float f32x4  __attribute__((ext_vector_type(4)));  // MFMA accumulator

// split f into hi + lo bf16 (hi = RNE(f), lo = RNE(f - hi); f-hi exact)
__device__ __forceinline__ void split_bf16(float f, unsigned short& h, unsigned short& l) {
  unsigned int u = __float_as_uint(f);
  unsigned int hb = (u + 0x7fffu + ((u >> 16) & 1u)) >> 16;
  h = (unsigned short)hb;
  float hf = __uint_as_float(hb << 16);
  float res = f - hf;
  unsigned int v = __float_as_uint(res);
  l = (unsigned short)((v + 0x7fffu + ((v >> 16) & 1u)) >> 16);
}
__device__ __forceinline__ float bf2f(unsigned short u) {
  return __uint_as_float((unsigned int)u << 16);
}

// ---------------------------------------------------------------------------
// Streaming split: fp32[n] -> hi bf16[n], lo bf16[n].  n4 = n/4.
// ---------------------------------------------------------------------------
__global__ __launch_bounds__(256) void convert_split(
    const float* __restrict__ in, unsigned short* __restrict__ hi,
    unsigned short* __restrict__ lo, int n4) {
  int idx = blockIdx.x * 256 + threadIdx.x;
  int stride = gridDim.x * 256;
  for (int i = idx; i < n4; i += stride) {
    float4 v = ((const float4*)in)[i];
    ushort4 h, l;
    split_bf16(v.x, h.x, l.x);
    split_bf16(v.y, h.y, l.y);
    split_bf16(v.z, h.z, l.z);
    split_bf16(v.w, h.w, l.w);
    ((ushort4*)hi)[i] = h;
    ((ushort4*)lo)[i] = l;
  }
}

// ---------------------------------------------------------------------------
// Transpose + split: W [K][N] fp32 row-major -> th/tl [N][K] bf16.
// ---------------------------------------------------------------------------
__global__ __launch_bounds__(256) void transpose_split(
    const float* __restrict__ W, unsigned short* __restrict__ th,
    unsigned short* __restrict__ tl, int K, int N) {
  __shared__ float tile[64][65];
  const int bk = blockIdx.y * 64;
  const int bn = blockIdx.x * 64;
  const int t  = threadIdx.x;
  const int r  = t >> 2;
  const int c0 = (t & 3) << 4;

#pragma unroll
  for (int c = 0; c < 16; c += 4) {
    float4 v = *(const float4*)(W + (size_t)(bk + r) * N + bn + c0 + c);
    tile[r][c0 + c + 0] = v.x; tile[r][c0 + c + 1] = v.y;
    tile[r][c0 + c + 2] = v.z; tile[r][c0 + c + 3] = v.w;
  }
  __syncthreads();

#pragma unroll
  for (int c = 0; c < 16; c += 4) {
    ushort4 h, l;
    split_bf16(tile[c0 + c + 0][r], h.x, l.x);
    split_bf16(tile[c0 + c + 1][r], h.y, l.y);
    split_bf16(tile[c0 + c + 2][r], h.z, l.z);
    split_bf16(tile[c0 + c + 3][r], h.w, l.w);
    size_t off = (size_t)(bn + r) * K + bk + c0 + c;
    *(ushort4*)(th + off) = h;
    *(ushort4*)(tl + off) = l;
  }
}

// ---------------------------------------------------------------------------
// Split-bf16 MFMA GEMM (HW-verified R6). BF16OUT writes hi/lo planes.
// ---------------------------------------------------------------------------
template <bool BF16OUT>
__global__ __launch_bounds__(256) void gemm_split(
    const unsigned short* __restrict__ Ah, const unsigned short* __restrict__ Al,
    const unsigned short* __restrict__ Bh, const unsigned short* __restrict__ Bl,
    float* __restrict__ C, unsigned short* __restrict__ Ch,
    unsigned short* __restrict__ Cl, int M, int N, int K) {
  __shared__ alignas(16) short sAh[128][32], sAl[128][32];
  __shared__ alignas(16) short sBh[128][32], sBl[128][32];
  const int t  = threadIdx.x;
  const int l  = t & 63;
  const int w  = t >> 6;
  const int bm = blockIdx.y * 128;
  const int bn = blockIdx.x * 128;
  const int wm = (w >> 1) * 64;
  const int wn = (w & 1) * 64;

  f32x4 acc[4][4] = {};

  for (int k0 = 0; k0 < K; k0 += 32) {
#pragma unroll
    for (int r = 0; r < 2; ++r) {
      const int i   = r * 256 + t;
      const int row = i >> 2;
      const int k8  = (i & 3) << 3;
      const size_t ga = (size_t)(bm + row) * K + k0 + k8;
      const size_t gb = (size_t)(bn + row) * K + k0 + k8;
      *(bf16x8*)(&sAh[row][k8]) = *(const bf16x8*)(Ah + ga);
      *(bf16x8*)(&sAl[row][k8]) = *(const bf16x8*)(Al + ga);
      *(bf16x8*)(&sBh[row][k8]) = *(const bf16x8*)(Bh + gb);
      *(bf16x8*)(&sBl[row][k8]) = *(const bf16x8*)(Bl + gb);
    }
    __syncthreads();

    bf16x8 ah[4], al4[4], bh[4], bl4[4];
    const int lr = l & 15;
    const int kk = (l >> 4) << 3;
#pragma unroll
    for (int mi = 0; mi < 4; ++mi) {
      const int row = wm + mi * 16 + lr;
      ah[mi]  = *(const bf16x8*)(&sAh[row][kk]);
      al4[mi] = *(const bf16x8*)(&sAl[row][kk]);
    }
#pragma unroll
    for (int ni = 0; ni < 4; ++ni) {
      const int row = wn + ni * 16 + lr;
      bh[ni]  = *(const bf16x8*)(&sBh[row][kk]);
      bl4[ni] = *(const bf16x8*)(&sBl[row][kk]);
    }

#pragma unroll
    for (int mi = 0; mi < 4; ++mi)
#pragma unroll
      for (int ni = 0; ni < 4; ++ni) {
        acc[mi][ni] = __builtin_amdgcn_mfma_f32_16x16x32_bf16(ah[mi],  bh[ni],  acc[mi][ni], 0, 0, 0);
        acc[mi][ni] = __builtin_amdgcn_mfma_f32_16x16x32_bf16(ah[mi],  bl4[ni], acc[mi][ni], 0, 0, 0);
        acc[mi][ni] = __builtin_amdgcn_mfma_f32_16x16x32_bf16(al4[mi], bh[ni],  acc[mi][ni], 0, 0, 0);
      }
    __syncthreads();
  }

  const int cr = (l >> 4) << 2;
  const int cc = l & 15;
#pragma unroll
  for (int mi = 0; mi < 4; ++mi)
#pragma unroll
    for (int ni = 0; ni < 4; ++ni) {
      const size_t base = (size_t)(bm + wm + mi * 16 + cr) * N + bn + wn + ni * 16 + cc;
#pragma unroll
      for (int r = 0; r < 4; ++r) {
        if constexpr (BF16OUT) {
          unsigned short hu, lu;
          split_bf16(acc[mi][ni][r], hu, lu);
          Ch[base + (size_t)r * N] = hu;
          Cl[base + (size_t)r * N] = lu;
        } else {
          C[base + (size_t)r * N] = acc[mi][ni][r];
        }
      }
    }
}

// ---------------------------------------------------------------------------
// Fused Yat causal attention, split-bf16 MFMA core.
// Block = (qb, b*16+h): 64 q-rows, 4 waves; wave w owns rows [16w,16w+16).
// LDS 36.5 KB -> 4 blocks/CU. Online softmax state in registers.
// Fragment conventions identical to gemm_split (HW-verified R6):
//   A/B frag: lane l reads [row: l&15][k: (l>>4)*8 ..+8]; D = A.B^T,
//   D elem: row=(l>>4)*4+reg, col=l&15.
// Phases/tile: stage K,V(+kn) | bar | QK MFMA + transform + softmax | bar |
//              P overlay-write (wave-local rows) + PV MFMA | bar.
// ---------------------------------------------------------------------------
__global__ __launch_bounds__(256, 4) void yat_attn_mfma(
    const unsigned short* __restrict__ qh, const unsigned short* __restrict__ ql,
    unsigned short* __restrict__ oh, unsigned short* __restrict__ ol) {
  const int qb = blockIdx.x;
  const int bh = blockIdx.y;
  const int b  = bh >> 4;
  const int h  = bh & 15;
  const size_t rs3 = 3 * C_DIM;   // qkv plane row stride (ushorts)
  const unsigned short* baseh = qh + (size_t)b * T_SEQ * rs3;
  const unsigned short* basel = ql + (size_t)b * T_SEQ * rs3;
  const int qcol = h * D_HEAD;
  const int kcol = C_DIM + h * D_HEAD;
  const int vcol = 2 * C_DIM + h * D_HEAD;

  // Kh/Kl triple-duty: Q staging (pre-loop) -> K tile -> P tile.
  __shared__ alignas(16) unsigned short Kh[64][72], Kl[64][72];
  __shared__ alignas(16) unsigned short Vth[64][72], Vtl[64][72];
  __shared__ float qn_row[64], kn_row[64];

  const int t = threadIdx.x;
  const int l = t & 63;
  const int w = t >> 6;
  const int lr   = l & 15;          // fragment row within 16-tile
  const int kk0  = (l >> 4) << 3;   // fragment k offset (0,8,16,24)
  const int rgrp = (l >> 4) << 2;   // C/D row base (0,4,8,12)

  // ---- stage Q (via K buffer) + qn; wave-local rows -> no barrier needed ----
  {
    const int row = t >> 2;               // 0..63 (wave w: rows 16w..16w+15)
    const int d0  = (t & 3) << 4;
    const size_t g = (size_t)(qb * 64 + row) * rs3 + qcol + d0;
    bf16x8 h0 = *(const bf16x8*)(baseh + g);
    bf16x8 h1 = *(const bf16x8*)(baseh + g + 8);
    bf16x8 l0 = *(const bf16x8*)(basel + g);
    bf16x8 l1 = *(const bf16x8*)(basel + g + 8);
    *(bf16x8*)(&Kh[row][d0])     = h0;
    *(bf16x8*)(&Kh[row][d0 + 8]) = h1;
    *(bf16x8*)(&Kl[row][d0])     = l0;
    *(bf16x8*)(&Kl[row][d0 + 8]) = l1;
    float s = 0.f;
#pragma unroll
    for (int i = 0; i < 8; ++i) {
      float f0 = bf2f((unsigned short)h0[i]) + bf2f((unsigned short)l0[i]);
      float f1 = bf2f((unsigned short)h1[i]) + bf2f((unsigned short)l1[i]);
      s = fmaf(f0, f0, s);
      s = fmaf(f1, f1, s);
    }
    s += __shfl_xor(s, 1);
    s += __shfl_xor(s, 2);
    if ((t & 3) == 0) qn_row[row] = s;
  }

  // ---- hoist Q fragments to registers (wave-local rows; DS in-order) ----
  const int ar = w * 16 + lr;
  bf16x8 qa_h0 = *(const bf16x8*)(&Kh[ar][kk0]);
  bf16x8 qa_h1 = *(const bf16x8*)(&Kh[ar][32 + kk0]);
  bf16x8 qa_l0 = *(const bf16x8*)(&Kl[ar][kk0]);
  bf16x8 qa_l1 = *(const bf16x8*)(&Kl[ar][32 + kk0]);

  float m_r[4] = {-INFINITY, -INFINITY, -INFINITY, -INFINITY};
  float l_r[4] = {0.f, 0.f, 0.f, 0.f};
  f32x4 o_acc[4] = {};
  float qn4[4];
#pragma unroll
  for (int r = 0; r < 4; ++r) qn4[r] = 0.f;   // loaded after first barrier

  __syncthreads();   // Q frags captured; qn_row visible; K buffer reusable
#pragma unroll
  for (int r = 0; r < 4; ++r) qn4[r] = qn_row[w * 16 + rgrp + r];

  for (int kb = 0; kb <= qb; ++kb) {
    // ---- stage K tile [j][d] + kn ----
    {
      const int row = t >> 2;
      const int d0  = (t & 3) << 4;
      const size_t g = (size_t)(kb * 64 + row) * rs3 + kcol + d0;
      bf16x8 h0 = *(const bf16x8*)(baseh + g);
      bf16x8 h1 = *(const bf16x8*)(baseh + g + 8);
      bf16x8 l0 = *(const bf16x8*)(basel + g);
      bf16x8 l1 = *(const bf16x8*)(basel + g + 8);
      *(bf16x8*)(&Kh[row][d0])     = h0;
      *(bf16x8*)(&Kh[row][d0 + 8]) = h1;
      *(bf16x8*)(&Kl[row][d0])     = l0;
      *(bf16x8*)(&Kl[row][d0 + 8]) = l1;
      float s = 0.f;
#pragma unroll
      for (int i = 0; i < 8; ++i) {
        float f0 = bf2f((unsigned short)h0[i]) + bf2f((unsigned short)l0[i]);
        float f1 = bf2f((unsigned short)h1[i]) + bf2f((unsigned short)l1[i]);
        s = fmaf(f0, f0, s);
        s = fmaf(f1, f1, s);
      }
      s += __shfl_xor(s, 1);
      s += __shfl_xor(s, 2);
      if ((t & 3) == 0) kn_row[row] = s;
    }
    // ---- stage V transposed Vt[d][j] ----
    {
      const int vj = l;
      const int d0 = w * 16;
      const size_t g = (size_t)(kb * 64 + vj) * rs3 + vcol + d0;
      bf16x8 h0 = *(const bf16x8*)(baseh + g);
      bf16x8 h1 = *(const bf16x8*)(baseh + g + 8);
      bf16x8 l0 = *(const bf16x8*)(basel + g);
      bf16x8 l1 = *(const bf16x8*)(basel + g + 8);
#pragma unroll
      for (int i = 0; i < 8; ++i) {
        Vth[d0 + i][vj]     = (unsigned short)h0[i];
        Vth[d0 + 8 + i][vj] = (unsigned short)h1[i];
        Vtl[d0 + i][vj]     = (unsigned short)l0[i];
        Vtl[d0 + 8 + i][vj] = (unsigned short)l1[i];
      }
    }
    __syncthreads();   // [1] K,V,kn staged

    // ---- QK^T MFMA: S rows [16w,16w+16), 4 col-tiles ----
    f32x4 s_acc[4] = {};
#pragma unroll
    for (int jt = 0; jt < 4; ++jt) {
      const int br = jt * 16 + lr;
      bf16x8 b_h0 = *(const bf16x8*)(&Kh[br][kk0]);
      bf16x8 b_h1 = *(const bf16x8*)(&Kh[br][32 + kk0]);
      bf16x8 b_l0 = *(const bf16x8*)(&Kl[br][kk0]);
      bf16x8 b_l1 = *(const bf16x8*)(&Kl[br][32 + kk0]);
      s_acc[jt] = __builtin_amdgcn_mfma_f32_16x16x32_bf16(qa_h0, b_h0, s_acc[jt], 0, 0, 0);
      s_acc[jt] = __builtin_amdgcn_mfma_f32_16x16x32_bf16(qa_h0, b_l0, s_acc[jt], 0, 0, 0);
      s_acc[jt] = __builtin_amdgcn_mfma_f32_16x16x32_bf16(qa_l0, b_h0, s_acc[jt], 0, 0, 0);
      s_acc[jt] = __builtin_amdgcn_mfma_f32_16x16x32_bf16(qa_h1, b_h1, s_acc[jt], 0, 0, 0);
      s_acc[jt] = __builtin_amdgcn_mfma_f32_16x16x32_bf16(qa_h1, b_l1, s_acc[jt], 0, 0, 0);
      s_acc[jt] = __builtin_amdgcn_mfma_f32_16x16x32_bf16(qa_l1, b_h1, s_acc[jt], 0, 0, 0);
    }

    // ---- Yat transform + causal mask (in-place in s_acc) ----
    {
      const bool diag = (kb == qb);
      const int gq0 = qb * 64 + w * 16 + rgrp;
#pragma unroll
      for (int jt = 0; jt < 4; ++jt) {
        const float kn = kn_row[jt * 16 + lr];
        const int gk = kb * 64 + jt * 16 + lr;
#pragma unroll
        for (int r = 0; r < 4; ++r) {
          const float dot = s_acc[jt][r];
          float sc = (dot * dot) / (qn4[r] + kn - 2.f * dot + EPS_Y);
          if (diag && gk > gq0 + r) sc = -INFINITY;
          s_acc[jt][r] = sc;
        }
      }
    }

    // ---- online softmax (state in regs; 16-lane row groups) ----
    float scale[4];
#pragma unroll
    for (int r = 0; r < 4; ++r) {
      float mm = fmaxf(fmaxf(s_acc[0][r], s_acc[1][r]),
                       fmaxf(s_acc[2][r], s_acc[3][r]));
      mm = fmaxf(mm, __shfl_xor(mm, 1));
      mm = fmaxf(mm, __shfl_xor(mm, 2));
      mm = fmaxf(mm, __shfl_xor(mm, 4));
      mm = fmaxf(mm, __shfl_xor(mm, 8));
      const float mnew = fmaxf(m_r[r], mm);
      scale[r] = __expf(m_r[r] - mnew);
      m_r[r] = mnew;
    }
#pragma unroll
    for (int r = 0; r < 4; ++r) {
      float lsum = 0.f;
#pragma unroll
      for (int jt = 0; jt < 4; ++jt) {
        float p = __expf(s_acc[jt][r] - m_r[r]);
        s_acc[jt][r] = p;
        lsum += p;
      }
      lsum += __shfl_xor(lsum, 1);
      lsum += __shfl_xor(lsum, 2);
      lsum += __shfl_xor(lsum, 4);
      lsum += __shfl_xor(lsum, 8);
      l_r[r] = l_r[r] * scale[r] + lsum;
    }
#pragma unroll
    for (int dt = 0; dt < 4; ++dt)
#pragma unroll
      for (int r = 0; r < 4; ++r) o_acc[dt][r] *= scale[r];

    __syncthreads();   // [2] all waves done reading K -> P may overlay

    // ---- write P (hi/lo) into K buffer; wave-local rows ----
#pragma unroll
    for (int jt = 0; jt < 4; ++jt)
#pragma unroll
      for (int r = 0; r < 4; ++r) {
        unsigned short hu, lu;
        split_bf16(s_acc[jt][r], hu, lu);
        const int prow = w * 16 + rgrp + r;
        Kh[prow][jt * 16 + lr] = hu;
        Kl[prow][jt * 16 + lr] = lu;
      }

    // ---- PV MFMA: A = P rows [16w,16w+16) (wave-local; DS in-order) ----
    {
      bf16x8 pa_h0 = *(const bf16x8*)(&Kh[ar][kk0]);
      bf16x8 pa_h1 = *(const bf16x8*)(&Kh[ar][32 + kk0]);
      bf16x8 pa_l0 = *(const bf16x8*)(&Kl[ar][kk0]);
      bf16x8 pa_l1 = *(const bf16x8*)(&Kl[ar][32 + kk0]);
#pragma unroll
      for (int dt = 0; dt < 4; ++dt) {
        const int vr = dt * 16 + lr;
        bf16x8 v_h0 = *(const bf16x8*)(&Vth[vr][kk0]);
        bf16x8 v_h1 = *(const bf16x8*)(&Vth[vr][32 + kk0]);
        bf16x8 v_l0 = *(const bf16x8*)(&Vtl[vr][kk0]);
        bf16x8 v_l1 = *(const bf16x8*)(&Vtl[vr][32 + kk0]);
        o_acc[dt] = __builtin_amdgcn_mfma_f32_16x16x32_bf16(pa_h0, v_h0, o_acc[dt], 0, 0, 0);
        o_acc[dt] = __builtin_amdgcn_mfma_f32_16x16x32_bf16(pa_h0, v_l0, o_acc[dt], 0, 0, 0);
        o_acc[dt] = __builtin_amdgcn_mfma_f32_16x16x32_bf16(pa_l0, v_h0, o_acc[dt], 0, 0, 0);
        o_acc[dt] = __builtin_amdgcn_mfma_f32_16x16x32_bf16(pa_h1, v_h1, o_acc[dt], 0, 0, 0);
        o_acc[dt] = __builtin_amdgcn_mfma_f32_16x16x32_bf16(pa_h1, v_l1, o_acc[dt], 0, 0, 0);
        o_acc[dt] = __builtin_amdgcn_mfma_f32_16x16x32_bf16(pa_l1, v_h1, o_acc[dt], 0, 0, 0);
      }
    }
    __syncthreads();   // [3] PV reads done -> next stage may overwrite
  }

  // ---- epilogue: O / l, split hi/lo, write planes ----
  float inv[4];
#pragma unroll
  for (int r = 0; r < 4; ++r) inv[r] = 1.f / l_r[r];
#pragma unroll
  for (int dt = 0; dt < 4; ++dt)
#pragma unroll
    for (int r = 0; r < 4; ++r) {
      float v = o_acc[dt][r] * inv[r];
      unsigned short hu, lu;
      split_bf16(v, hu, lu);
      const size_t off = ((size_t)b * T_SEQ + qb * 64 + w * 16 + rgrp + r) * C_DIM
                         + h * D_HEAD + dt * 16 + lr;
      oh[off] = hu;
      ol[off] = lu;
    }
}

// ---------------------------------------------------------------------------
extern "C" void kernel_launch(void* const* d_in, const int* in_sizes, int n_in,
                              void* d_out, int out_size, void* d_ws, size_t ws_size,
                              hipStream_t stream) {
  const float* x    = (const float*)d_in[0];   // [B,T,C]
  const float* Wqkv = (const float*)d_in[1];   // [C,3C]
  const float* Wout = (const float*)d_in[2];   // [C,C]
  float* outp = (float*)d_out;                 // [B,T,C]

  const int M  = B_BATCH * T_SEQ;              // 4096
  const int C3 = 3 * C_DIM;                    // 3072

  // workspace (all ushort planes, ~100.6 MB)
  unsigned short* xh   = (unsigned short*)d_ws;
  unsigned short* xl   = xh   + (size_t)M * C_DIM;
  unsigned short* wqh  = xl   + (size_t)M * C_DIM;     // Wqkv^T [3C][C]
  unsigned short* wql  = wqh  + (size_t)C_DIM * C3;
  unsigned short* woh  = wql  + (size_t)C_DIM * C3;    // Wout^T [C][C]
  unsigned short* wol  = woh  + (size_t)C_DIM * C_DIM;
  unsigned short* qkvh = wol  + (size_t)C_DIM * C_DIM; // qkv hi [M][3C]
  unsigned short* qkvl = qkvh + (size_t)M * C3;
  unsigned short* ath  = qkvl + (size_t)M * C3;        // attn out hi [M][C]
  unsigned short* atl  = ath  + (size_t)M * C_DIM;

  // 1) split x
  convert_split<<<2048, 256, 0, stream>>>(x, xh, xl, M * C_DIM / 4);
  // 2) transpose+split weights
  {
    dim3 g1(C3 / 64, C_DIM / 64);
    transpose_split<<<g1, 256, 0, stream>>>(Wqkv, wqh, wql, C_DIM, C3);
    dim3 g2(C_DIM / 64, C_DIM / 64);
    transpose_split<<<g2, 256, 0, stream>>>(Wout, woh, wol, C_DIM, C_DIM);
  }
  // 3) qkv = x @ Wqkv -> split bf16 planes directly
  {
    dim3 grid(C3 / 128, M / 128);
    gemm_split<true><<<grid, 256, 0, stream>>>(xh, xl, wqh, wql,
                                               nullptr, qkvh, qkvl, M, C3, C_DIM);
  }
  // 4) fused Yat causal attention (MFMA core)
  {
    dim3 grid(T_SEQ / 64, B_BATCH * H_HEADS);
    yat_attn_mfma<<<grid, 256, 0, stream>>>(qkvh, qkvl, ath, atl);
  }
  // 5) out = attn @ Wout (fp32 out)
  {
    dim3 grid(C_DIM / 128, M / 128);
    gemm_split<false><<<grid, 256, 0, stream>>>(ath, atl, woh, wol,
                                                outp, nullptr, nullptr, M, C_DIM, C_DIM);
  }
  (void)in_sizes; (void)n_in; (void)out_size; (void)ws_size;
}

// Round 9
// 393.063 us; speedup vs baseline: 2.0322x; 1.1636x over previous
//
#include <hip/hip_runtime.h>

#define T_SEQ   2048
#define C_DIM   1024
#define B_BATCH 2
#define H_HEADS 16
#define D_HEAD  64
#define EPS_Y   1e-6f

typedef short bf16x8 __attribute__((ext_vector_type(8)));  // 8 bf16 (4 VGPR)
typedef float f32x4  __attribute__((ext_vector_type(4)));  // MFMA accumulator

// split f into hi + lo bf16 (hi = RNE(f), lo = RNE(f - hi); f-hi exact)
__device__ __forceinline__ void split_bf16(float f, unsigned short& h, unsigned short& l) {
  unsigned int u = __float_as_uint(f);
  unsigned int hb = (u + 0x7fffu + ((u >> 16) & 1u)) >> 16;
  h = (unsigned short)hb;
  float hf = __uint_as_float(hb << 16);
  float res = f - hf;
  unsigned int v = __float_as_uint(res);
  l = (unsigned short)((v + 0x7fffu + ((v >> 16) & 1u)) >> 16);
}
__device__ __forceinline__ float bf2f(unsigned short u) {
  return __uint_as_float((unsigned int)u << 16);
}

// ---------------------------------------------------------------------------
// Streaming split: fp32[n] -> hi bf16[n], lo bf16[n].  n4 = n/4.
// ---------------------------------------------------------------------------
__global__ __launch_bounds__(256) void convert_split(
    const float* __restrict__ in, unsigned short* __restrict__ hi,
    unsigned short* __restrict__ lo, int n4) {
  int idx = blockIdx.x * 256 + threadIdx.x;
  int stride = gridDim.x * 256;
  for (int i = idx; i < n4; i += stride) {
    float4 v = ((const float4*)in)[i];
    ushort4 h, l;
    split_bf16(v.x, h.x, l.x);
    split_bf16(v.y, h.y, l.y);
    split_bf16(v.z, h.z, l.z);
    split_bf16(v.w, h.w, l.w);
    ((ushort4*)hi)[i] = h;
    ((ushort4*)lo)[i] = l;
  }
}

// ---------------------------------------------------------------------------
// Transpose + split: W [K][N] fp32 row-major -> th/tl [N][K] bf16.
// ---------------------------------------------------------------------------
__global__ __launch_bounds__(256) void transpose_split(
    const float* __restrict__ W, unsigned short* __restrict__ th,
    unsigned short* __restrict__ tl, int K, int N) {
  __shared__ float tile[64][65];
  const int bk = blockIdx.y * 64;
  const int bn = blockIdx.x * 64;
  const int t  = threadIdx.x;
  const int r  = t >> 2;
  const int c0 = (t & 3) << 4;

#pragma unroll
  for (int c = 0; c < 16; c += 4) {
    float4 v = *(const float4*)(W + (size_t)(bk + r) * N + bn + c0 + c);
    tile[r][c0 + c + 0] = v.x; tile[r][c0 + c + 1] = v.y;
    tile[r][c0 + c + 2] = v.z; tile[r][c0 + c + 3] = v.w;
  }
  __syncthreads();

#pragma unroll
  for (int c = 0; c < 16; c += 4) {
    ushort4 h, l;
    split_bf16(tile[c0 + c + 0][r], h.x, l.x);
    split_bf16(tile[c0 + c + 1][r], h.y, l.y);
    split_bf16(tile[c0 + c + 2][r], h.z, l.z);
    split_bf16(tile[c0 + c + 3][r], h.w, l.w);
    size_t off = (size_t)(bn + r) * K + bk + c0 + c;
    *(ushort4*)(th + off) = h;
    *(ushort4*)(tl + off) = l;
  }
}

// ---------------------------------------------------------------------------
// Row norms of q and k planes: qn/kn[(b*H+h)*T + t] = sum_d q(k)^2.
// One 16-lane group per (b,t,h); block covers 16 heads of one (b,t) row.
// ---------------------------------------------------------------------------
__global__ __launch_bounds__(256) void row_norms(
    const unsigned short* __restrict__ qkvh, const unsigned short* __restrict__ qkvl,
    float* __restrict__ qnG, float* __restrict__ knG) {
  const int t    = threadIdx.x;
  const int g    = blockIdx.x * 16 + (t >> 4);   // (b*T + trow)*H + h
  const int lane = t & 15;
  const int h    = g & (H_HEADS - 1);
  const int bt   = g >> 4;                        // b*T + trow
  const int b    = bt >> 11;                      // T = 2048
  const int trow = bt & (T_SEQ - 1);
  const size_t rowbase = (size_t)bt * (3 * C_DIM);
  const size_t outi = ((size_t)(b * H_HEADS + h)) * T_SEQ + trow;

#pragma unroll
  for (int plane = 0; plane < 2; ++plane) {
    const size_t off = rowbase + (plane ? C_DIM : 0) + h * D_HEAD + lane * 4;
    ushort4 hh = *(const ushort4*)(qkvh + off);
    ushort4 ll = *(const ushort4*)(qkvl + off);
    float f0 = bf2f(hh.x) + bf2f(ll.x);
    float f1 = bf2f(hh.y) + bf2f(ll.y);
    float f2 = bf2f(hh.z) + bf2f(ll.z);
    float f3 = bf2f(hh.w) + bf2f(ll.w);
    float s = f0 * f0 + f1 * f1 + f2 * f2 + f3 * f3;
    s += __shfl_xor(s, 1);
    s += __shfl_xor(s, 2);
    s += __shfl_xor(s, 4);
    s += __shfl_xor(s, 8);
    if (lane == 0) {
      if (plane == 0) qnG[outi] = s; else knG[outi] = s;
    }
  }
}

// ---------------------------------------------------------------------------
// Split-bf16 MFMA GEMM (HW-verified R6). BF16OUT writes hi/lo planes.
// ---------------------------------------------------------------------------
template <bool BF16OUT>
__global__ __launch_bounds__(256) void gemm_split(
    const unsigned short* __restrict__ Ah, const unsigned short* __restrict__ Al,
    const unsigned short* __restrict__ Bh, const unsigned short* __restrict__ Bl,
    float* __restrict__ C, unsigned short* __restrict__ Ch,
    unsigned short* __restrict__ Cl, int M, int N, int K) {
  __shared__ alignas(16) short sAh[128][32], sAl[128][32];
  __shared__ alignas(16) short sBh[128][32], sBl[128][32];
  const int t  = threadIdx.x;
  const int l  = t & 63;
  const int w  = t >> 6;
  const int bm = blockIdx.y * 128;
  const int bn = blockIdx.x * 128;
  const int wm = (w >> 1) * 64;
  const int wn = (w & 1) * 64;

  f32x4 acc[4][4] = {};

  for (int k0 = 0; k0 < K; k0 += 32) {
#pragma unroll
    for (int r = 0; r < 2; ++r) {
      const int i   = r * 256 + t;
      const int row = i >> 2;
      const int k8  = (i & 3) << 3;
      const size_t ga = (size_t)(bm + row) * K + k0 + k8;
      const size_t gb = (size_t)(bn + row) * K + k0 + k8;
      *(bf16x8*)(&sAh[row][k8]) = *(const bf16x8*)(Ah + ga);
      *(bf16x8*)(&sAl[row][k8]) = *(const bf16x8*)(Al + ga);
      *(bf16x8*)(&sBh[row][k8]) = *(const bf16x8*)(Bh + gb);
      *(bf16x8*)(&sBl[row][k8]) = *(const bf16x8*)(Bl + gb);
    }
    __syncthreads();

    bf16x8 ah[4], al4[4], bh[4], bl4[4];
    const int lr = l & 15;
    const int kk = (l >> 4) << 3;
#pragma unroll
    for (int mi = 0; mi < 4; ++mi) {
      const int row = wm + mi * 16 + lr;
      ah[mi]  = *(const bf16x8*)(&sAh[row][kk]);
      al4[mi] = *(const bf16x8*)(&sAl[row][kk]);
    }
#pragma unroll
    for (int ni = 0; ni < 4; ++ni) {
      const int row = wn + ni * 16 + lr;
      bh[ni]  = *(const bf16x8*)(&sBh[row][kk]);
      bl4[ni] = *(const bf16x8*)(&sBl[row][kk]);
    }

#pragma unroll
    for (int mi = 0; mi < 4; ++mi)
#pragma unroll
      for (int ni = 0; ni < 4; ++ni) {
        acc[mi][ni] = __builtin_amdgcn_mfma_f32_16x16x32_bf16(ah[mi],  bh[ni],  acc[mi][ni], 0, 0, 0);
        acc[mi][ni] = __builtin_amdgcn_mfma_f32_16x16x32_bf16(ah[mi],  bl4[ni], acc[mi][ni], 0, 0, 0);
        acc[mi][ni] = __builtin_amdgcn_mfma_f32_16x16x32_bf16(al4[mi], bh[ni],  acc[mi][ni], 0, 0, 0);
      }
    __syncthreads();
  }

  const int cr = (l >> 4) << 2;
  const int cc = l & 15;
#pragma unroll
  for (int mi = 0; mi < 4; ++mi)
#pragma unroll
    for (int ni = 0; ni < 4; ++ni) {
      const size_t base = (size_t)(bm + wm + mi * 16 + cr) * N + bn + wn + ni * 16 + cc;
#pragma unroll
      for (int r = 0; r < 4; ++r) {
        if constexpr (BF16OUT) {
          unsigned short hu, lu;
          split_bf16(acc[mi][ni][r], hu, lu);
          Ch[base + (size_t)r * N] = hu;
          Cl[base + (size_t)r * N] = lu;
        } else {
          C[base + (size_t)r * N] = acc[mi][ni][r];
        }
      }
    }
}

// ---------------------------------------------------------------------------
// Fused Yat causal attention, split-bf16 MFMA core (structure HW-verified R8).
// R9 changes: (a) qn/kn precomputed (row_norms) -> hot loop has no reduces,
// no Q LDS staging; (b) complementary q-tile pairing {qb, 31-qb}: every block
// does exactly 33 tile-iters -> no causal-triangle tail; (c) fast rcp.
// Block = (qb0, b*16+h): 4 waves, wave w owns rows [16w,16w+16) of each tile.
// ---------------------------------------------------------------------------
__global__ __launch_bounds__(256, 4) void yat_attn_mfma(
    const unsigned short* __restrict__ qh, const unsigned short* __restrict__ ql,
    const float* __restrict__ qnG, const float* __restrict__ knG,
    unsigned short* __restrict__ oh, unsigned short* __restrict__ ol) {
  const int qb0 = blockIdx.x;           // 0..15
  const int bh  = blockIdx.y;           // 0..31 == b*16+h
  const int b   = bh >> 4;
  const int h   = bh & 15;
  const size_t rs3 = 3 * C_DIM;
  const unsigned short* baseh = qh + (size_t)b * T_SEQ * rs3;
  const unsigned short* basel = ql + (size_t)b * T_SEQ * rs3;
  const int qcol = h * D_HEAD;
  const int kcol = C_DIM + h * D_HEAD;
  const int vcol = 2 * C_DIM + h * D_HEAD;
  const size_t nbase = (size_t)bh * T_SEQ;   // norms base for this (b,h)

  // Kh/Kl double-duty: K tile -> P tile.
  __shared__ alignas(16) unsigned short Kh[64][72], Kl[64][72];
  __shared__ alignas(16) unsigned short Vth[64][72], Vtl[64][72];

  const int t = threadIdx.x;
  const int l = t & 63;
  const int w = t >> 6;
  const int lr   = l & 15;          // fragment row within 16-tile
  const int kk0  = (l >> 4) << 3;   // fragment k offset (0,8,16,24)
  const int rgrp = (l >> 4) << 2;   // C/D row base (0,4,8,12)
  const int ar   = w * 16 + lr;     // this wave's A-fragment row

  for (int half = 0; half < 2; ++half) {
    const int qt = half ? (31 - qb0) : qb0;   // q-tile index 0..31

    // ---- Q fragments direct from global (once per q-tile; L2-hot) ----
    const size_t qg = (size_t)(qt * 64 + ar) * rs3 + qcol;
    bf16x8 qa_h0 = *(const bf16x8*)(baseh + qg + kk0);
    bf16x8 qa_h1 = *(const bf16x8*)(baseh + qg + 32 + kk0);
    bf16x8 qa_l0 = *(const bf16x8*)(basel + qg + kk0);
    bf16x8 qa_l1 = *(const bf16x8*)(basel + qg + 32 + kk0);

    float qn4[4];
#pragma unroll
    for (int r = 0; r < 4; ++r)
      qn4[r] = qnG[nbase + qt * 64 + w * 16 + rgrp + r];

    float m_r[4] = {-INFINITY, -INFINITY, -INFINITY, -INFINITY};
    float l_r[4] = {0.f, 0.f, 0.f, 0.f};
    f32x4 o_acc[4] = {};

    for (int kb = 0; kb <= qt; ++kb) {
      // ---- stage K tile [j][d] ----
      {
        const int row = t >> 2;
        const int d0  = (t & 3) << 4;
        const size_t g = (size_t)(kb * 64 + row) * rs3 + kcol + d0;
        *(bf16x8*)(&Kh[row][d0])     = *(const bf16x8*)(baseh + g);
        *(bf16x8*)(&Kh[row][d0 + 8]) = *(const bf16x8*)(baseh + g + 8);
        *(bf16x8*)(&Kl[row][d0])     = *(const bf16x8*)(basel + g);
        *(bf16x8*)(&Kl[row][d0 + 8]) = *(const bf16x8*)(basel + g + 8);
      }
      // ---- stage V transposed Vt[d][j] (wave w owns d rows 16w..16w+15) ----
      {
        const int vj = l;
        const int d0 = w * 16;
        const size_t g = (size_t)(kb * 64 + vj) * rs3 + vcol + d0;
        bf16x8 h0 = *(const bf16x8*)(baseh + g);
        bf16x8 h1 = *(const bf16x8*)(baseh + g + 8);
        bf16x8 l0 = *(const bf16x8*)(basel + g);
        bf16x8 l1 = *(const bf16x8*)(basel + g + 8);
#pragma unroll
        for (int i = 0; i < 8; ++i) {
          Vth[d0 + i][vj]     = (unsigned short)h0[i];
          Vth[d0 + 8 + i][vj] = (unsigned short)h1[i];
          Vtl[d0 + i][vj]     = (unsigned short)l0[i];
          Vtl[d0 + 8 + i][vj] = (unsigned short)l1[i];
        }
      }
      // ---- kn for this tile (precomputed; issue early, L2-hot) ----
      float knv[4];
#pragma unroll
      for (int jt = 0; jt < 4; ++jt)
        knv[jt] = knG[nbase + kb * 64 + jt * 16 + lr];

      __syncthreads();   // [1] K,V staged

      // ---- QK^T MFMA: S rows [16w,16w+16), 4 col-tiles ----
      f32x4 s_acc[4] = {};
#pragma unroll
      for (int jt = 0; jt < 4; ++jt) {
        const int br = jt * 16 + lr;
        bf16x8 b_h0 = *(const bf16x8*)(&Kh[br][kk0]);
        bf16x8 b_h1 = *(const bf16x8*)(&Kh[br][32 + kk0]);
        bf16x8 b_l0 = *(const bf16x8*)(&Kl[br][kk0]);
        bf16x8 b_l1 = *(const bf16x8*)(&Kl[br][32 + kk0]);
        s_acc[jt] = __builtin_amdgcn_mfma_f32_16x16x32_bf16(qa_h0, b_h0, s_acc[jt], 0, 0, 0);
        s_acc[jt] = __builtin_amdgcn_mfma_f32_16x16x32_bf16(qa_h0, b_l0, s_acc[jt], 0, 0, 0);
        s_acc[jt] = __builtin_amdgcn_mfma_f32_16x16x32_bf16(qa_l0, b_h0, s_acc[jt], 0, 0, 0);
        s_acc[jt] = __builtin_amdgcn_mfma_f32_16x16x32_bf16(qa_h1, b_h1, s_acc[jt], 0, 0, 0);
        s_acc[jt] = __builtin_amdgcn_mfma_f32_16x16x32_bf16(qa_h1, b_l1, s_acc[jt], 0, 0, 0);
        s_acc[jt] = __builtin_amdgcn_mfma_f32_16x16x32_bf16(qa_l1, b_h1, s_acc[jt], 0, 0, 0);
      }

      // ---- Yat transform + causal mask ----
      {
        const bool diag = (kb == qt);
        const int gq0 = qt * 64 + w * 16 + rgrp;
#pragma unroll
        for (int jt = 0; jt < 4; ++jt) {
          const int gk = kb * 64 + jt * 16 + lr;
#pragma unroll
          for (int r = 0; r < 4; ++r) {
            const float dot = s_acc[jt][r];
            const float den = qn4[r] + knv[jt] - 2.f * dot + EPS_Y;
            float sc = (dot * dot) * __builtin_amdgcn_rcpf(den);
            if (diag && gk > gq0 + r) sc = -INFINITY;
            s_acc[jt][r] = sc;
          }
        }
      }

      // ---- online softmax (state in regs; 16-lane row groups) ----
      float scale[4];
#pragma unroll
      for (int r = 0; r < 4; ++r) {
        float mm = fmaxf(fmaxf(s_acc[0][r], s_acc[1][r]),
                         fmaxf(s_acc[2][r], s_acc[3][r]));
        mm = fmaxf(mm, __shfl_xor(mm, 1));
        mm = fmaxf(mm, __shfl_xor(mm, 2));
        mm = fmaxf(mm, __shfl_xor(mm, 4));
        mm = fmaxf(mm, __shfl_xor(mm, 8));
        const float mnew = fmaxf(m_r[r], mm);
        scale[r] = __expf(m_r[r] - mnew);
        m_r[r] = mnew;
      }
#pragma unroll
      for (int r = 0; r < 4; ++r) {
        float lsum = 0.f;
#pragma unroll
        for (int jt = 0; jt < 4; ++jt) {
          float p = __expf(s_acc[jt][r] - m_r[r]);
          s_acc[jt][r] = p;
          lsum += p;
        }
        lsum += __shfl_xor(lsum, 1);
        lsum += __shfl_xor(lsum, 2);
        lsum += __shfl_xor(lsum, 4);
        lsum += __shfl_xor(lsum, 8);
        l_r[r] = l_r[r] * scale[r] + lsum;
      }
#pragma unroll
      for (int dt = 0; dt < 4; ++dt)
#pragma unroll
        for (int r = 0; r < 4; ++r) o_acc[dt][r] *= scale[r];

      __syncthreads();   // [2] all waves done reading K -> P may overlay

      // ---- write P (hi/lo) into K buffer; wave-local rows ----
#pragma unroll
      for (int jt = 0; jt < 4; ++jt)
#pragma unroll
        for (int r = 0; r < 4; ++r) {
          unsigned short hu, lu;
          split_bf16(s_acc[jt][r], hu, lu);
          const int prow = w * 16 + rgrp + r;
          Kh[prow][jt * 16 + lr] = hu;
          Kl[prow][jt * 16 + lr] = lu;
        }

      // ---- PV MFMA: A = P rows [16w,16w+16) (wave-local; DS in-order) ----
      {
        bf16x8 pa_h0 = *(const bf16x8*)(&Kh[ar][kk0]);
        bf16x8 pa_h1 = *(const bf16x8*)(&Kh[ar][32 + kk0]);
        bf16x8 pa_l0 = *(const bf16x8*)(&Kl[ar][kk0]);
        bf16x8 pa_l1 = *(const bf16x8*)(&Kl[ar][32 + kk0]);
#pragma unroll
        for (int dt = 0; dt < 4; ++dt) {
          const int vr = dt * 16 + lr;
          bf16x8 v_h0 = *(const bf16x8*)(&Vth[vr][kk0]);
          bf16x8 v_h1 = *(const bf16x8*)(&Vth[vr][32 + kk0]);
          bf16x8 v_l0 = *(const bf16x8*)(&Vtl[vr][kk0]);
          bf16x8 v_l1 = *(const bf16x8*)(&Vtl[vr][32 + kk0]);
          o_acc[dt] = __builtin_amdgcn_mfma_f32_16x16x32_bf16(pa_h0, v_h0, o_acc[dt], 0, 0, 0);
          o_acc[dt] = __builtin_amdgcn_mfma_f32_16x16x32_bf16(pa_h0, v_l0, o_acc[dt], 0, 0, 0);
          o_acc[dt] = __builtin_amdgcn_mfma_f32_16x16x32_bf16(pa_l0, v_h0, o_acc[dt], 0, 0, 0);
          o_acc[dt] = __builtin_amdgcn_mfma_f32_16x16x32_bf16(pa_h1, v_h1, o_acc[dt], 0, 0, 0);
          o_acc[dt] = __builtin_amdgcn_mfma_f32_16x16x32_bf16(pa_h1, v_l1, o_acc[dt], 0, 0, 0);
          o_acc[dt] = __builtin_amdgcn_mfma_f32_16x16x32_bf16(pa_l1, v_h1, o_acc[dt], 0, 0, 0);
        }
      }
      __syncthreads();   // [3] PV reads done -> next stage may overwrite
    }

    // ---- epilogue for this q-tile: O / l, split hi/lo, write ----
    float inv[4];
#pragma unroll
    for (int r = 0; r < 4; ++r) inv[r] = 1.f / l_r[r];
#pragma unroll
    for (int dt = 0; dt < 4; ++dt)
#pragma unroll
      for (int r = 0; r < 4; ++r) {
        float v = o_acc[dt][r] * inv[r];
        unsigned short hu, lu;
        split_bf16(v, hu, lu);
        const size_t off = ((size_t)b * T_SEQ + qt * 64 + w * 16 + rgrp + r) * C_DIM
                           + h * D_HEAD + dt * 16 + lr;
        oh[off] = hu;
        ol[off] = lu;
      }
  }
}

// ---------------------------------------------------------------------------
extern "C" void kernel_launch(void* const* d_in, const int* in_sizes, int n_in,
                              void* d_out, int out_size, void* d_ws, size_t ws_size,
                              hipStream_t stream) {
  const float* x    = (const float*)d_in[0];   // [B,T,C]
  const float* Wqkv = (const float*)d_in[1];   // [C,3C]
  const float* Wout = (const float*)d_in[2];   // [C,C]
  float* outp = (float*)d_out;                 // [B,T,C]

  const int M  = B_BATCH * T_SEQ;              // 4096
  const int C3 = 3 * C_DIM;                    // 3072

  // workspace (all ushort planes, ~100.6 MB)
  unsigned short* xh   = (unsigned short*)d_ws;
  unsigned short* xl   = xh   + (size_t)M * C_DIM;
  unsigned short* wqh  = xl   + (size_t)M * C_DIM;     // Wqkv^T [3C][C]
  unsigned short* wql  = wqh  + (size_t)C_DIM * C3;
  unsigned short* woh  = wql  + (size_t)C_DIM * C3;    // Wout^T [C][C]
  unsigned short* wol  = woh  + (size_t)C_DIM * C_DIM;
  unsigned short* qkvh = wol  + (size_t)C_DIM * C_DIM; // qkv hi [M][3C]
  unsigned short* qkvl = qkvh + (size_t)M * C3;
  unsigned short* ath  = qkvl + (size_t)M * C3;        // attn out hi [M][C]
  unsigned short* atl  = ath  + (size_t)M * C_DIM;
  // qn/kn overlay the xh buffer (dead after gemm1): [B*H*T] f32 each
  float* qnG = (float*)xh;                             // 256 KB
  float* knG = qnG + (size_t)B_BATCH * H_HEADS * T_SEQ;

  // 1) split x
  convert_split<<<2048, 256, 0, stream>>>(x, xh, xl, M * C_DIM / 4);
  // 2) transpose+split weights
  {
    dim3 g1(C3 / 64, C_DIM / 64);
    transpose_split<<<g1, 256, 0, stream>>>(Wqkv, wqh, wql, C_DIM, C3);
    dim3 g2(C_DIM / 64, C_DIM / 64);
    transpose_split<<<g2, 256, 0, stream>>>(Wout, woh, wol, C_DIM, C_DIM);
  }
  // 3) qkv = x @ Wqkv -> split bf16 planes directly
  {
    dim3 grid(C3 / 128, M / 128);
    gemm_split<true><<<grid, 256, 0, stream>>>(xh, xl, wqh, wql,
                                               nullptr, qkvh, qkvl, M, C3, C_DIM);
  }
  // 4) qn/kn norms (xh is dead now; qnG/knG overlay it)
  row_norms<<<M * H_HEADS / 16, 256, 0, stream>>>(qkvh, qkvl, qnG, knG);
  // 5) fused Yat causal attention (MFMA core, paired q-tiles)
  {
    dim3 grid(T_SEQ / 64 / 2, B_BATCH * H_HEADS);
    yat_attn_mfma<<<grid, 256, 0, stream>>>(qkvh, qkvl, qnG, knG, ath, atl);
  }
  // 6) out = attn @ Wout (fp32 out)
  {
    dim3 grid(C_DIM / 128, M / 128);
    gemm_split<false><<<grid, 256, 0, stream>>>(ath, atl, woh, wol,
                                                outp, nullptr, nullptr, M, C_DIM, C_DIM);
  }
  (void)in_sizes; (void)n_in; (void)out_size; (void)ws_size;
}